// Round 15
// baseline (91196.552 us; speedup 1.0000x reference)
//
#include <hip/hip_runtime.h>
#include <math.h>
#include <stdint.h>

// ReLSTM_18940805775611 — B=512, T=128, H=512, 2-layer LSTM:
// 128 teacher-forced steps, then 127 autoregressive steps.
//
// World model v5 (R1-R14 forensics, all observations explained):
//  - inputs fp32 (R8's bf16-decode NaN proved not-bf16), OUTPUT FP32 TOO:
//    R10-R14 wrote bf16 (128KB) into a 256KB fp32-read buffer -> u16 pairs
//    reinterpret as floats ~= y[2i+1] + mantissa noise, half-buffer zeros ->
//    absmax ~2.08e-2 EXACTLY as observed, bit-stable because the y0 fix only
//    perturbs out_float[0]'s low mantissa bits (y-feedback gain ~5e-4/step:
//    contractive scalar bottleneck through w_ih0). R5/R8 NaN = bf16 NaNs
//    reinterpreted as fp32. Test label "(bf16...)" is a hardcoded f-string.
//  - Reference quirk kept: y0 = state[3] @ w_lin.T + b_lin, state=(h1,c1,h2,c2)
//    -> FIRST prediction from CELL state c2; AR predictions from h2.
//  - This round: d_out treated as float*. Sentinel 2.5f (distinguishes
//    truncation). All else structurally identical to the known-building R10
//    skeleton; symbols renamed again to dodge any name-keyed artifact cache.

namespace {
constexpr int NH = 512;   // hidden size
constexpr int NT = 128;   // sequence length
constexpr int NB = 512;   // batch
constexpr int TB = 32;    // batch rows per block
constexpr int TO = 16;    // h-outputs per block
constexpr int TK = 64;    // k-chunk staged in LDS
}

// Present in case the harness resolves this symbol.
__global__ void ReLSTM_18940805775611_kernel() {}

__device__ __forceinline__ float lstm5_sig(float x) {
    return 1.0f / (1.0f + expf(-x));
}

// ---- sentinel 2.5f: if the chain truncates, absmax ~= 2.5 (diagnostic) ----
__global__ void lstm5_mark(float* out) {
    const int i = blockIdx.x * blockDim.x + threadIdx.x;
    if (i < NB * NT) out[i] = 2.5f;
}

// ---- zero states; y := b_lin ----
__global__ void lstm5_clear(float* states, float* ybuf, const float* blin) {
    const size_t stride = (size_t)gridDim.x * blockDim.x;
    const size_t i0 = (size_t)blockIdx.x * blockDim.x + threadIdx.x;
    const size_t nState = (size_t)6 * NB * NH;
    for (size_t i = i0; i < nState; i += stride) states[i] = 0.0f;
    const float bl = blin[0];
    for (size_t i = i0; i < (size_t)NB * NT; i += stride) ybuf[i] = bl;
}

// ---- layer-0 cell: gates = x*w_ih0 + hPrev @ w_hh0^T + (b_ih0+b_hh0) ----
__global__ __launch_bounds__(256) void lstm5_layer0(
    const float* __restrict__ xin, const float* __restrict__ ybuf,
    int col, int useY, int pubCol, float* __restrict__ outf,
    const float* __restrict__ hPrev, float* __restrict__ hNext,
    float* __restrict__ cell,
    const float* __restrict__ wih, const float* __restrict__ whh,
    const float* __restrict__ bih, const float* __restrict__ bhh)
{
    __shared__ float hstage[TB][TK + 2];
    const int tid  = threadIdx.x;
    const int ocol = tid & (TO - 1);
    const int brow = tid >> 4;
    const int bbase = blockIdx.x * TB;
    const int oidx  = blockIdx.y * TO + ocol;
    const int row0 = bbase + brow, row1 = bbase + brow + 16;

    // publish the just-completed y column to d_out (one block only, fp32)
    if (pubCol >= 0 && blockIdx.x == 0 && blockIdx.y == 0) {
        for (int r = tid; r < NB; r += 256)
            outf[(size_t)r * NT + pubCol] = ybuf[(size_t)r * NT + pubCol];
    }

    float x0, x1;
    if (useY) {
        x0 = ybuf[(size_t)row0 * NT + col];
        x1 = ybuf[(size_t)row1 * NT + col];
    } else {
        x0 = xin[(size_t)row0 * NT + col];
        x1 = xin[(size_t)row1 * NT + col];
    }

    const float bgi = bih[oidx]          + bhh[oidx];
    const float bgf = bih[oidx + NH]     + bhh[oidx + NH];
    const float bgg = bih[oidx + 2 * NH] + bhh[oidx + 2 * NH];
    const float bgo = bih[oidx + 3 * NH] + bhh[oidx + 3 * NH];
    const float wxi = wih[oidx];
    const float wxf = wih[oidx + NH];
    const float wxg = wih[oidx + 2 * NH];
    const float wxo = wih[oidx + 3 * NH];

    float gi0 = fmaf(x0, wxi, bgi), gi1 = fmaf(x1, wxi, bgi);
    float gf0 = fmaf(x0, wxf, bgf), gf1 = fmaf(x1, wxf, bgf);
    float gg0 = fmaf(x0, wxg, bgg), gg1 = fmaf(x1, wxg, bgg);
    float go0 = fmaf(x0, wxo, bgo), go1 = fmaf(x1, wxo, bgo);

    const size_t rowI = (size_t)(oidx         ) * NH;
    const size_t rowF = (size_t)(oidx +     NH) * NH;
    const size_t rowG = (size_t)(oidx + 2 * NH) * NH;
    const size_t rowO = (size_t)(oidx + 3 * NH) * NH;

    for (int kc = 0; kc < NH; kc += TK) {
        int lin = tid * 2;
        for (int it = 0; it < 4; ++it, lin += 512) {
            const int r = lin >> 6, cc = lin & (TK - 1);
            *(float2*)&hstage[r][cc] =
                *(const float2*)(hPrev + (size_t)(bbase + r) * NH + kc + cc);
        }
        __syncthreads();
        #pragma unroll 8
        for (int k = 0; k < TK; k += 2) {
            const float2 wvi = *(const float2*)(whh + rowI + kc + k);
            const float2 wvf = *(const float2*)(whh + rowF + kc + k);
            const float2 wvg = *(const float2*)(whh + rowG + kc + k);
            const float2 wvo = *(const float2*)(whh + rowO + kc + k);
            const float a0 = hstage[brow][k],      a1 = hstage[brow][k + 1];
            const float b0 = hstage[brow + 16][k], b1 = hstage[brow + 16][k + 1];
            gi0 = fmaf(a0, wvi.x, gi0); gi0 = fmaf(a1, wvi.y, gi0);
            gi1 = fmaf(b0, wvi.x, gi1); gi1 = fmaf(b1, wvi.y, gi1);
            gf0 = fmaf(a0, wvf.x, gf0); gf0 = fmaf(a1, wvf.y, gf0);
            gf1 = fmaf(b0, wvf.x, gf1); gf1 = fmaf(b1, wvf.y, gf1);
            gg0 = fmaf(a0, wvg.x, gg0); gg0 = fmaf(a1, wvg.y, gg0);
            gg1 = fmaf(b0, wvg.x, gg1); gg1 = fmaf(b1, wvg.y, gg1);
            go0 = fmaf(a0, wvo.x, go0); go0 = fmaf(a1, wvo.y, go0);
            go1 = fmaf(b0, wvo.x, go1); go1 = fmaf(b1, wvo.y, go1);
        }
        __syncthreads();
    }

    {
        float cv = cell[(size_t)row0 * NH + oidx];
        cv = lstm5_sig(gf0) * cv + lstm5_sig(gi0) * tanhf(gg0);
        cell[(size_t)row0 * NH + oidx] = cv;
        hNext[(size_t)row0 * NH + oidx] = lstm5_sig(go0) * tanhf(cv);
    }
    {
        float cv = cell[(size_t)row1 * NH + oidx];
        cv = lstm5_sig(gf1) * cv + lstm5_sig(gi1) * tanhf(gg1);
        cell[(size_t)row1 * NH + oidx] = cv;
        hNext[(size_t)row1 * NH + oidx] = lstm5_sig(go1) * tanhf(cv);
    }
}

// ---- layer-1 cell (+ fused AR y-head from h2 when ycol >= 0) ----
__global__ __launch_bounds__(256) void lstm5_layer1(
    const float* __restrict__ h1Cur, const float* __restrict__ h2Prev,
    float* __restrict__ h2Next, float* __restrict__ cell,
    const float* __restrict__ wih, const float* __restrict__ whh,
    const float* __restrict__ bih, const float* __restrict__ bhh,
    const float* __restrict__ wlin, float* __restrict__ ybuf, int ycol)
{
    __shared__ float s1[TB][TK + 2];
    __shared__ float s2[TB][TK + 2];
    __shared__ float acc[TB][TO + 1];
    const int tid  = threadIdx.x;
    const int ocol = tid & (TO - 1);
    const int brow = tid >> 4;
    const int bbase = blockIdx.x * TB;
    const int oidx  = blockIdx.y * TO + ocol;
    const int row0 = bbase + brow, row1 = bbase + brow + 16;

    float gi0 = bih[oidx]          + bhh[oidx];
    float gf0 = bih[oidx + NH]     + bhh[oidx + NH];
    float gg0 = bih[oidx + 2 * NH] + bhh[oidx + 2 * NH];
    float go0 = bih[oidx + 3 * NH] + bhh[oidx + 3 * NH];
    float gi1 = gi0, gf1 = gf0, gg1 = gg0, go1 = go0;

    const size_t rowI = (size_t)(oidx         ) * NH;
    const size_t rowF = (size_t)(oidx +     NH) * NH;
    const size_t rowG = (size_t)(oidx + 2 * NH) * NH;
    const size_t rowO = (size_t)(oidx + 3 * NH) * NH;

    for (int kc = 0; kc < NH; kc += TK) {
        int lin = tid * 2;
        for (int it = 0; it < 4; ++it, lin += 512) {
            const int r = lin >> 6, cc = lin & (TK - 1);
            *(float2*)&s1[r][cc] =
                *(const float2*)(h1Cur + (size_t)(bbase + r) * NH + kc + cc);
            *(float2*)&s2[r][cc] =
                *(const float2*)(h2Prev + (size_t)(bbase + r) * NH + kc + cc);
        }
        __syncthreads();
        #pragma unroll 4
        for (int k = 0; k < TK; k += 2) {
            const float2 ui = *(const float2*)(wih + rowI + kc + k);
            const float2 uf = *(const float2*)(wih + rowF + kc + k);
            const float2 ug = *(const float2*)(wih + rowG + kc + k);
            const float2 uo = *(const float2*)(wih + rowO + kc + k);
            const float2 vi = *(const float2*)(whh + rowI + kc + k);
            const float2 vf = *(const float2*)(whh + rowF + kc + k);
            const float2 vg = *(const float2*)(whh + rowG + kc + k);
            const float2 vo = *(const float2*)(whh + rowO + kc + k);
            const float p0 = s1[brow][k],      p1 = s1[brow][k + 1];
            const float p2 = s1[brow + 16][k], p3 = s1[brow + 16][k + 1];
            const float q0 = s2[brow][k],      q1 = s2[brow][k + 1];
            const float q2 = s2[brow + 16][k], q3 = s2[brow + 16][k + 1];
            gi0 = fmaf(p0, ui.x, gi0); gi0 = fmaf(p1, ui.y, gi0);
            gi1 = fmaf(p2, ui.x, gi1); gi1 = fmaf(p3, ui.y, gi1);
            gf0 = fmaf(p0, uf.x, gf0); gf0 = fmaf(p1, uf.y, gf0);
            gf1 = fmaf(p2, uf.x, gf1); gf1 = fmaf(p3, uf.y, gf1);
            gg0 = fmaf(p0, ug.x, gg0); gg0 = fmaf(p1, ug.y, gg0);
            gg1 = fmaf(p2, ug.x, gg1); gg1 = fmaf(p3, ug.y, gg1);
            go0 = fmaf(p0, uo.x, go0); go0 = fmaf(p1, uo.y, go0);
            go1 = fmaf(p2, uo.x, go1); go1 = fmaf(p3, uo.y, go1);
            gi0 = fmaf(q0, vi.x, gi0); gi0 = fmaf(q1, vi.y, gi0);
            gi1 = fmaf(q2, vi.x, gi1); gi1 = fmaf(q3, vi.y, gi1);
            gf0 = fmaf(q0, vf.x, gf0); gf0 = fmaf(q1, vf.y, gf0);
            gf1 = fmaf(q2, vf.x, gf1); gf1 = fmaf(q3, vf.y, gf1);
            gg0 = fmaf(q0, vg.x, gg0); gg0 = fmaf(q1, vg.y, gg0);
            gg1 = fmaf(q2, vg.x, gg1); gg1 = fmaf(q3, vg.y, gg1);
            go0 = fmaf(q0, vo.x, go0); go0 = fmaf(q1, vo.y, go0);
            go1 = fmaf(q2, vo.x, go1); go1 = fmaf(q3, vo.y, go1);
        }
        __syncthreads();
    }

    float h0, h1;
    {
        float cv = cell[(size_t)row0 * NH + oidx];
        cv = lstm5_sig(gf0) * cv + lstm5_sig(gi0) * tanhf(gg0);
        cell[(size_t)row0 * NH + oidx] = cv;
        h0 = lstm5_sig(go0) * tanhf(cv);
        h2Next[(size_t)row0 * NH + oidx] = h0;
    }
    {
        float cv = cell[(size_t)row1 * NH + oidx];
        cv = lstm5_sig(gf1) * cv + lstm5_sig(gi1) * tanhf(gg1);
        cell[(size_t)row1 * NH + oidx] = cv;
        h1 = lstm5_sig(go1) * tanhf(cv);
        h2Next[(size_t)row1 * NH + oidx] = h1;
    }

    if (ycol >= 0) {
        const float wl = wlin[oidx];
        acc[brow][ocol]      = h0 * wl;
        acc[brow + 16][ocol] = h1 * wl;
        __syncthreads();
        if (tid < TB) {
            float s = 0.0f;
            for (int j = 0; j < TO; ++j) s += acc[tid][j];
            atomicAdd(&ybuf[(size_t)(bbase + tid) * NT + ycol], s);
        }
    }
}

// ---- y0 head (reference quirk): y[:,0] = b_lin + c2 @ w_lin  (CELL state!) ----
__global__ __launch_bounds__(256) void lstm5_head(
    const float* __restrict__ c2, const float* __restrict__ wlin,
    const float* __restrict__ blin, float* __restrict__ ybuf)
{
    __shared__ float acc[256];
    const int b   = blockIdx.x;
    const int tid = threadIdx.x;
    acc[tid] = c2[(size_t)b * NH + tid]       * wlin[tid]
             + c2[(size_t)b * NH + tid + 256] * wlin[tid + 256];
    __syncthreads();
    for (int off = 128; off > 0; off >>= 1) {
        if (tid < off) acc[tid] += acc[tid + off];
        __syncthreads();
    }
    if (tid == 0) ybuf[(size_t)b * NT] = blin[0] + acc[0];
}

// ---- final: all predictions to d_out as fp32 ----
__global__ void lstm5_emit(const float* __restrict__ ybuf,
                           float* __restrict__ out) {
    const int i = blockIdx.x * blockDim.x + threadIdx.x;
    if (i < NB * NT) out[i] = ybuf[i];
}

extern "C" void kernel_launch(void* const* d_in, const int* in_sizes, int n_in,
                              void* d_out, int out_size, void* d_ws, size_t ws_size,
                              hipStream_t stream)
{
    // Inputs in setup_inputs() order; x_time/y_time (idx 1,2) unused. Anchor on
    // the first 4*NH-sized array (= w_ih0) in case unused inputs were pruned.
    int base = 3;
    if (!(n_in > 3 && in_sizes[3] == 4 * NH)) {
        for (int i = 1; i + 9 < n_in; ++i)
            if (in_sizes[i] == 4 * NH) { base = i; break; }
    }
    const float* xin  = (const float*)d_in[0];
    const float* wih0 = (const float*)d_in[base + 0];
    const float* whh0 = (const float*)d_in[base + 1];
    const float* bih0 = (const float*)d_in[base + 2];
    const float* bhh0 = (const float*)d_in[base + 3];
    const float* wih1 = (const float*)d_in[base + 4];
    const float* whh1 = (const float*)d_in[base + 5];
    const float* bih1 = (const float*)d_in[base + 6];
    const float* bhh1 = (const float*)d_in[base + 7];
    const float* wlin = (const float*)d_in[base + 8];
    const float* blin = (const float*)d_in[base + 9];
    float* outf = (float*)d_out;

    // ws: f32 states (6*NB*NH = 6 MB) | f32 y (256 KB). ~6.3 MB total.
    const size_t S = (size_t)NB * NH;
    float* states = (float*)d_ws;
    float* ybuf   = states + 6 * S;

    lstm5_mark<<<(NB * NT + 255) / 256, 256, 0, stream>>>(outf);
    lstm5_clear<<<512, 256, 0, stream>>>(states, ybuf, blin);

    float* h1p[2] = { states,         states + S };
    float* c1     =   states + 2 * S;
    float* h2p[2] = { states + 3 * S, states + 4 * S };
    float* c2     =   states + 5 * S;

    dim3 grid(NB / TB, NH / TO);   // 16 x 32 = 512 blocks
    int p = 0;
    // Phase 1: teacher-forced; heads disabled (y0 handled by lstm5_head).
    for (int t = 0; t < NT; ++t) {
        lstm5_layer0<<<grid, 256, 0, stream>>>(xin, ybuf, t, 0, -1, outf,
                                               h1p[p], h1p[p ^ 1], c1,
                                               wih0, whh0, bih0, bhh0);
        lstm5_layer1<<<grid, 256, 0, stream>>>(h1p[p ^ 1], h2p[p], h2p[p ^ 1], c2,
                                               wih1, whh1, bih1, bhh1,
                                               wlin, ybuf, -1);
        p ^= 1;
    }
    // Reference quirk: first prediction from the CELL state c2.
    lstm5_head<<<NB, 256, 0, stream>>>(c2, wlin, blin, ybuf);
    // Phase 2: autoregressive; layer0 consumes y[:,k-1] and publishes it;
    // heads from h2.
    for (int k = 1; k < NT; ++k) {
        lstm5_layer0<<<grid, 256, 0, stream>>>(xin, ybuf, k - 1, 1, k - 1, outf,
                                               h1p[p], h1p[p ^ 1], c1,
                                               wih0, whh0, bih0, bhh0);
        lstm5_layer1<<<grid, 256, 0, stream>>>(h1p[p ^ 1], h2p[p], h2p[p ^ 1], c2,
                                               wih1, whh1, bih1, bhh1,
                                               wlin, ybuf, k);
        p ^= 1;
    }
    lstm5_emit<<<(NB * NT + 255) / 256, 256, 0, stream>>>(ybuf, outf);
}

// Round 16
// 19271.411 us; speedup vs baseline: 4.7322x; 4.7322x over previous
//
#include <hip/hip_runtime.h>
#include <math.h>
#include <stdint.h>

// ReLSTM_18940805775611 — B=512, T=128, H=512, 2-layer LSTM:
// 128 teacher-forced steps + 127 AR steps. fp32 in / fp32 out (R15 PASSED:
// absmax 3.05e-5, dur 91.2 ms). Reference quirk kept: y0 from CELL state c2.
//
// R16 optimization: R15's inner loop read weights with per-lane divergent
// global loads (16 distinct 2KB-strided rows per wave -> ~16 transactions per
// instr; TA-issue-bound, ~358 us per step pair). This round stages weight
// tiles into LDS with coalesced float4 loads (256B per 16-lane group) and
// reads them back as ds_read_b128 with <=2-way bank aliasing (free, m136) +
// 4-fold broadcast. Inner 4-k step: 64 FMA (128 cyc/wave) vs ~26 LDS cyc ->
// VALU-bound. Predicted ~5.2 ms compute + dispatch overhead => 10-14 ms.

namespace {
constexpr int NH = 512;   // hidden size
constexpr int NT = 128;   // sequence length
constexpr int NB = 512;   // batch
constexpr int TB = 32;    // batch rows per block
constexpr int TO = 16;    // h-outputs per block
constexpr int TK = 64;    // k-chunk staged in LDS
}

// Present in case the harness resolves this symbol.
__global__ void ReLSTM_18940805775611_kernel() {}

__device__ __forceinline__ float lstm6_sig(float x) {
    return 1.0f / (1.0f + expf(-x));
}

// ---- sentinel 2.25f: truncation diagnostic (distinct from R15's 2.5f) ----
__global__ void lstm6_mark(float* out) {
    const int i = blockIdx.x * blockDim.x + threadIdx.x;
    if (i < NB * NT) out[i] = 2.25f;
}

// ---- zero states; y := b_lin ----
__global__ void lstm6_clear(float* states, float* ybuf, const float* blin) {
    const size_t stride = (size_t)gridDim.x * blockDim.x;
    const size_t i0 = (size_t)blockIdx.x * blockDim.x + threadIdx.x;
    const size_t nState = (size_t)6 * NB * NH;
    for (size_t i = i0; i < nState; i += stride) states[i] = 0.0f;
    const float bl = blin[0];
    for (size_t i = i0; i < (size_t)NB * NT; i += stride) ybuf[i] = bl;
}

// ---- layer-0 cell: gates = x*w_ih0 + hPrev @ w_hh0^T + (b_ih0+b_hh0) ----
__global__ __launch_bounds__(256) void lstm6_layer0(
    const float* __restrict__ xin, const float* __restrict__ ybuf,
    int col, int useY, int pubCol, float* __restrict__ outf,
    const float* __restrict__ hPrev, float* __restrict__ hNext,
    float* __restrict__ cell,
    const float* __restrict__ wih, const float* __restrict__ whh,
    const float* __restrict__ bih, const float* __restrict__ bhh)
{
    __shared__ float wsh[64][TK + 4];   // 4 gates x 16 ocols of w_hh0
    __shared__ float hsh[TB][TK + 4];
    const int tid  = threadIdx.x;
    const int ocol = tid & (TO - 1);
    const int brow = tid >> 4;
    const int bbase = blockIdx.x * TB;
    const int oidx  = blockIdx.y * TO + ocol;
    const int row0 = bbase + brow, row1 = bbase + brow + 16;

    // publish the just-completed y column to d_out (one block only, fp32)
    if (pubCol >= 0 && blockIdx.x == 0 && blockIdx.y == 0) {
        for (int r = tid; r < NB; r += 256)
            outf[(size_t)r * NT + pubCol] = ybuf[(size_t)r * NT + pubCol];
    }

    float x0, x1;
    if (useY) {
        x0 = ybuf[(size_t)row0 * NT + col];
        x1 = ybuf[(size_t)row1 * NT + col];
    } else {
        x0 = xin[(size_t)row0 * NT + col];
        x1 = xin[(size_t)row1 * NT + col];
    }

    float g0[4], g1[4];
    #pragma unroll
    for (int g = 0; g < 4; ++g) {
        const float bb = bih[oidx + g * NH] + bhh[oidx + g * NH];
        const float wx = wih[oidx + g * NH];
        g0[g] = fmaf(x0, wx, bb);
        g1[g] = fmaf(x1, wx, bb);
    }

    const int oybase = blockIdx.y * TO;
    for (int kc = 0; kc < NH; kc += TK) {
        #pragma unroll
        for (int rep = 0; rep < 4; ++rep) {
            const int lin = tid + rep * 256;          // 0..1023
            const int r = lin >> 4, seg = lin & 15;   // row 0..63, seg 0..15
            const int grow = (r >> 4) * NH + oybase + (r & 15);
            *(float4*)&wsh[r][seg * 4] =
                *(const float4*)(whh + (size_t)grow * NH + kc + seg * 4);
        }
        #pragma unroll
        for (int rep = 0; rep < 2; ++rep) {
            const int lin = tid + rep * 256;          // 0..511
            const int r = lin >> 4, seg = lin & 15;
            *(float4*)&hsh[r][seg * 4] =
                *(const float4*)(hPrev + (size_t)(bbase + r) * NH + kc + seg * 4);
        }
        __syncthreads();
        #pragma unroll 2
        for (int k = 0; k < TK; k += 4) {
            const float4 a = *(const float4*)&hsh[brow][k];
            const float4 b = *(const float4*)&hsh[brow + 16][k];
            #pragma unroll
            for (int g = 0; g < 4; ++g) {
                const float4 w = *(const float4*)&wsh[g * 16 + ocol][k];
                g0[g] = fmaf(a.x, w.x, g0[g]); g0[g] = fmaf(a.y, w.y, g0[g]);
                g0[g] = fmaf(a.z, w.z, g0[g]); g0[g] = fmaf(a.w, w.w, g0[g]);
                g1[g] = fmaf(b.x, w.x, g1[g]); g1[g] = fmaf(b.y, w.y, g1[g]);
                g1[g] = fmaf(b.z, w.z, g1[g]); g1[g] = fmaf(b.w, w.w, g1[g]);
            }
        }
        __syncthreads();
    }

    {
        float cv = cell[(size_t)row0 * NH + oidx];
        cv = lstm6_sig(g0[1]) * cv + lstm6_sig(g0[0]) * tanhf(g0[2]);
        cell[(size_t)row0 * NH + oidx] = cv;
        hNext[(size_t)row0 * NH + oidx] = lstm6_sig(g0[3]) * tanhf(cv);
    }
    {
        float cv = cell[(size_t)row1 * NH + oidx];
        cv = lstm6_sig(g1[1]) * cv + lstm6_sig(g1[0]) * tanhf(g1[2]);
        cell[(size_t)row1 * NH + oidx] = cv;
        hNext[(size_t)row1 * NH + oidx] = lstm6_sig(g1[3]) * tanhf(cv);
    }
}

// ---- layer-1 cell (+ fused AR y-head from h2 when ycol >= 0) ----
__global__ __launch_bounds__(256) void lstm6_layer1(
    const float* __restrict__ h1Cur, const float* __restrict__ h2Prev,
    float* __restrict__ h2Next, float* __restrict__ cell,
    const float* __restrict__ wih, const float* __restrict__ whh,
    const float* __restrict__ bih, const float* __restrict__ bhh,
    const float* __restrict__ wlin, float* __restrict__ ybuf, int ycol)
{
    __shared__ float wish[64][TK + 4];   // w_ih1 tile
    __shared__ float whsh[64][TK + 4];   // w_hh1 tile
    __shared__ float h1sh[TB][TK + 4];
    __shared__ float h2sh[TB][TK + 4];
    __shared__ float acc[TB][TO + 1];
    const int tid  = threadIdx.x;
    const int ocol = tid & (TO - 1);
    const int brow = tid >> 4;
    const int bbase = blockIdx.x * TB;
    const int oidx  = blockIdx.y * TO + ocol;
    const int row0 = bbase + brow, row1 = bbase + brow + 16;

    float g0[4], g1[4];
    #pragma unroll
    for (int g = 0; g < 4; ++g) {
        const float bb = bih[oidx + g * NH] + bhh[oidx + g * NH];
        g0[g] = bb;
        g1[g] = bb;
    }

    const int oybase = blockIdx.y * TO;
    for (int kc = 0; kc < NH; kc += TK) {
        #pragma unroll
        for (int rep = 0; rep < 4; ++rep) {
            const int lin = tid + rep * 256;
            const int r = lin >> 4, seg = lin & 15;
            const int grow = (r >> 4) * NH + oybase + (r & 15);
            *(float4*)&wish[r][seg * 4] =
                *(const float4*)(wih + (size_t)grow * NH + kc + seg * 4);
            *(float4*)&whsh[r][seg * 4] =
                *(const float4*)(whh + (size_t)grow * NH + kc + seg * 4);
        }
        #pragma unroll
        for (int rep = 0; rep < 2; ++rep) {
            const int lin = tid + rep * 256;
            const int r = lin >> 4, seg = lin & 15;
            *(float4*)&h1sh[r][seg * 4] =
                *(const float4*)(h1Cur + (size_t)(bbase + r) * NH + kc + seg * 4);
            *(float4*)&h2sh[r][seg * 4] =
                *(const float4*)(h2Prev + (size_t)(bbase + r) * NH + kc + seg * 4);
        }
        __syncthreads();
        #pragma unroll 2
        for (int k = 0; k < TK; k += 4) {
            const float4 p0 = *(const float4*)&h1sh[brow][k];
            const float4 p1 = *(const float4*)&h1sh[brow + 16][k];
            const float4 q0 = *(const float4*)&h2sh[brow][k];
            const float4 q1 = *(const float4*)&h2sh[brow + 16][k];
            #pragma unroll
            for (int g = 0; g < 4; ++g) {
                const float4 u = *(const float4*)&wish[g * 16 + ocol][k];
                const float4 v = *(const float4*)&whsh[g * 16 + ocol][k];
                g0[g] = fmaf(p0.x, u.x, g0[g]); g0[g] = fmaf(p0.y, u.y, g0[g]);
                g0[g] = fmaf(p0.z, u.z, g0[g]); g0[g] = fmaf(p0.w, u.w, g0[g]);
                g0[g] = fmaf(q0.x, v.x, g0[g]); g0[g] = fmaf(q0.y, v.y, g0[g]);
                g0[g] = fmaf(q0.z, v.z, g0[g]); g0[g] = fmaf(q0.w, v.w, g0[g]);
                g1[g] = fmaf(p1.x, u.x, g1[g]); g1[g] = fmaf(p1.y, u.y, g1[g]);
                g1[g] = fmaf(p1.z, u.z, g1[g]); g1[g] = fmaf(p1.w, u.w, g1[g]);
                g1[g] = fmaf(q1.x, v.x, g1[g]); g1[g] = fmaf(q1.y, v.y, g1[g]);
                g1[g] = fmaf(q1.z, v.z, g1[g]); g1[g] = fmaf(q1.w, v.w, g1[g]);
            }
        }
        __syncthreads();
    }

    float h0, h1;
    {
        float cv = cell[(size_t)row0 * NH + oidx];
        cv = lstm6_sig(g0[1]) * cv + lstm6_sig(g0[0]) * tanhf(g0[2]);
        cell[(size_t)row0 * NH + oidx] = cv;
        h0 = lstm6_sig(g0[3]) * tanhf(cv);
        h2Next[(size_t)row0 * NH + oidx] = h0;
    }
    {
        float cv = cell[(size_t)row1 * NH + oidx];
        cv = lstm6_sig(g1[1]) * cv + lstm6_sig(g1[0]) * tanhf(g1[2]);
        cell[(size_t)row1 * NH + oidx] = cv;
        h1 = lstm6_sig(g1[3]) * tanhf(cv);
        h2Next[(size_t)row1 * NH + oidx] = h1;
    }

    if (ycol >= 0) {
        const float wl = wlin[oidx];
        acc[brow][ocol]      = h0 * wl;
        acc[brow + 16][ocol] = h1 * wl;
        __syncthreads();
        if (tid < TB) {
            float s = 0.0f;
            for (int j = 0; j < TO; ++j) s += acc[tid][j];
            atomicAdd(&ybuf[(size_t)(bbase + tid) * NT + ycol], s);
        }
    }
}

// ---- y0 head (reference quirk): y[:,0] = b_lin + c2 @ w_lin  (CELL state!) ----
__global__ __launch_bounds__(256) void lstm6_head(
    const float* __restrict__ c2, const float* __restrict__ wlin,
    const float* __restrict__ blin, float* __restrict__ ybuf)
{
    __shared__ float acc[256];
    const int b   = blockIdx.x;
    const int tid = threadIdx.x;
    acc[tid] = c2[(size_t)b * NH + tid]       * wlin[tid]
             + c2[(size_t)b * NH + tid + 256] * wlin[tid + 256];
    __syncthreads();
    for (int off = 128; off > 0; off >>= 1) {
        if (tid < off) acc[tid] += acc[tid + off];
        __syncthreads();
    }
    if (tid == 0) ybuf[(size_t)b * NT] = blin[0] + acc[0];
}

// ---- final: all predictions to d_out as fp32 ----
__global__ void lstm6_emit(const float* __restrict__ ybuf,
                           float* __restrict__ out) {
    const int i = blockIdx.x * blockDim.x + threadIdx.x;
    if (i < NB * NT) out[i] = ybuf[i];
}

extern "C" void kernel_launch(void* const* d_in, const int* in_sizes, int n_in,
                              void* d_out, int out_size, void* d_ws, size_t ws_size,
                              hipStream_t stream)
{
    int base = 3;
    if (!(n_in > 3 && in_sizes[3] == 4 * NH)) {
        for (int i = 1; i + 9 < n_in; ++i)
            if (in_sizes[i] == 4 * NH) { base = i; break; }
    }
    const float* xin  = (const float*)d_in[0];
    const float* wih0 = (const float*)d_in[base + 0];
    const float* whh0 = (const float*)d_in[base + 1];
    const float* bih0 = (const float*)d_in[base + 2];
    const float* bhh0 = (const float*)d_in[base + 3];
    const float* wih1 = (const float*)d_in[base + 4];
    const float* whh1 = (const float*)d_in[base + 5];
    const float* bih1 = (const float*)d_in[base + 6];
    const float* bhh1 = (const float*)d_in[base + 7];
    const float* wlin = (const float*)d_in[base + 8];
    const float* blin = (const float*)d_in[base + 9];
    float* outf = (float*)d_out;

    // ws: f32 states (6*NB*NH = 6 MB) | f32 y (256 KB). ~6.3 MB total.
    const size_t S = (size_t)NB * NH;
    float* states = (float*)d_ws;
    float* ybuf   = states + 6 * S;

    lstm6_mark<<<(NB * NT + 255) / 256, 256, 0, stream>>>(outf);
    lstm6_clear<<<512, 256, 0, stream>>>(states, ybuf, blin);

    float* h1p[2] = { states,         states + S };
    float* c1     =   states + 2 * S;
    float* h2p[2] = { states + 3 * S, states + 4 * S };
    float* c2     =   states + 5 * S;

    dim3 grid(NB / TB, NH / TO);   // 16 x 32 = 512 blocks, 2/CU
    int p = 0;
    // Phase 1: teacher-forced; heads disabled (y0 handled by lstm6_head).
    for (int t = 0; t < NT; ++t) {
        lstm6_layer0<<<grid, 256, 0, stream>>>(xin, ybuf, t, 0, -1, outf,
                                               h1p[p], h1p[p ^ 1], c1,
                                               wih0, whh0, bih0, bhh0);
        lstm6_layer1<<<grid, 256, 0, stream>>>(h1p[p ^ 1], h2p[p], h2p[p ^ 1], c2,
                                               wih1, whh1, bih1, bhh1,
                                               wlin, ybuf, -1);
        p ^= 1;
    }
    // Reference quirk: first prediction from the CELL state c2.
    lstm6_head<<<NB, 256, 0, stream>>>(c2, wlin, blin, ybuf);
    // Phase 2: autoregressive; layer0 consumes y[:,k-1] and publishes it.
    for (int k = 1; k < NT; ++k) {
        lstm6_layer0<<<grid, 256, 0, stream>>>(xin, ybuf, k - 1, 1, k - 1, outf,
                                               h1p[p], h1p[p ^ 1], c1,
                                               wih0, whh0, bih0, bhh0);
        lstm6_layer1<<<grid, 256, 0, stream>>>(h1p[p ^ 1], h2p[p], h2p[p ^ 1], c2,
                                               wih1, whh1, bih1, bhh1,
                                               wlin, ybuf, k);
        p ^= 1;
    }
    lstm6_emit<<<(NB * NT + 255) / 256, 256, 0, stream>>>(ybuf, outf);
}

// Round 17
// 6061.744 us; speedup vs baseline: 15.0446x; 3.1792x over previous
//
#include <hip/hip_runtime.h>
#include <math.h>
#include <stdint.h>

// ReLSTM_18940805775611 — B=512, T=128, H=512, 2-layer LSTM, 128 TF + 127 AR
// steps. fp32 in / fp32 out. R16 (fp32 LDS-tiled): 19.27 ms, absmax 3.05e-5,
// LDS-bandwidth-bound (3 B/FLOP vs 1 B/FLOP available; 3x oversubscribed).
// R17: bf16 MFMA (16x16x32, fp32 accumulate). Weights/h bf16 (one-time prep
// kernel), c-state fp32. Block = 64 batch x 16 j x 4 gates; each wave: 16-row
// tile, 4 gate-accumulators -> each lane holds all 4 gates of its (m,j) after
// the verified C/D map (col=lane&15, row=quad*4+reg), so the LSTM epilogue is
// lane-local. A/B frags: lane reads 8 contiguous bf16 (A[m=lane&15][k=quad*8+j],
// B mirrored) from +8-padded LDS (2-way alias = free). l1 = two K=512 phases.
// Accuracy budget: 14x margin at fp32; bf16 per-step gate error ~3e-5,
// contractive recurrence -> predicted absmax ~1e-4 < 4.39e-4 threshold.
// Reference quirk kept: y0 from CELL state c2 (standalone head kernel).

namespace {
constexpr int NH  = 512;   // hidden
constexpr int NT  = 128;   // seq len
constexpr int NB  = 512;   // batch
constexpr int KC  = 64;    // k-chunk
constexpr int LDK = KC + 8; // LDS row stride in bf16 elems (144 B, banks skewed)
}

typedef __attribute__((ext_vector_type(8))) short bf16x8;
typedef __attribute__((ext_vector_type(4))) float f32x4;

// Present in case the harness resolves this symbol.
__global__ void ReLSTM_18940805775611_kernel() {}

__device__ __forceinline__ unsigned short lstm7_f2b(float f) {
    union { float f; uint32_t i; } v; v.f = f;
    const uint32_t r = v.i + 0x7FFFu + ((v.i >> 16) & 1u);   // RNE
    return (unsigned short)(r >> 16);
}
__device__ __forceinline__ float lstm7_sig(float x) {
    return 1.0f / (1.0f + expf(-x));
}

// ---- sentinel 2.125f: truncation diagnostic ----
__global__ void lstm7_mark(float* out) {
    const int i = blockIdx.x * blockDim.x + threadIdx.x;
    if (i < NB * NT) out[i] = 2.125f;
}

// ---- one-time prep: weights fp32->bf16 (RNE), summed biases, zero states,
// ybuf := b_lin ----
__global__ void lstm7_prep(
    const float* whh0, const float* wih1, const float* whh1,
    const float* bih0, const float* bhh0, const float* bih1, const float* bhh1,
    const float* blin,
    unsigned short* wb0, unsigned short* wb1i, unsigned short* wb1h,
    float* bsum0, float* bsum1,
    unsigned short* hz, float* cz, float* ybuf)
{
    const size_t stride = (size_t)gridDim.x * blockDim.x;
    const size_t i0 = (size_t)blockIdx.x * blockDim.x + threadIdx.x;
    const size_t NW = (size_t)4 * NH * NH;               // 1M elems per matrix
    for (size_t i = i0; i < NW; i += stride) {
        wb0 [i] = lstm7_f2b(whh0[i]);
        wb1i[i] = lstm7_f2b(wih1[i]);
        wb1h[i] = lstm7_f2b(whh1[i]);
    }
    for (size_t i = i0; i < (size_t)4 * NH; i += stride) {
        bsum0[i] = bih0[i] + bhh0[i];
        bsum1[i] = bih1[i] + bhh1[i];
    }
    for (size_t i = i0; i < (size_t)4 * NB * NH; i += stride) hz[i] = 0;  // h1[2],h2[2]
    for (size_t i = i0; i < (size_t)2 * NB * NH; i += stride) cz[i] = 0.0f; // c1,c2
    const float bl = blin[0];
    for (size_t i = i0; i < (size_t)NB * NT; i += stride) ybuf[i] = bl;
}

// ---- layer-0 MFMA cell: gates = x*w_ih0 + hPrev @ w_hh0^T + bsum0 ----
// grid (8, 32): x = batch/64, y = j/16. 256 threads = 4 waves x 16 rows.
__global__ __launch_bounds__(256) void lstm7_layer0(
    const float* __restrict__ xin, float* __restrict__ ybuf,
    int col, int useY, int pubCol, float* __restrict__ outf,
    const unsigned short* __restrict__ hprev, unsigned short* __restrict__ hnext,
    float* __restrict__ c1,
    const unsigned short* __restrict__ wb0,
    const float* __restrict__ bsum0, const float* __restrict__ wih0f)
{
    __shared__ unsigned short Ash[64][LDK];
    __shared__ unsigned short Bsh[64][LDK];
    const int tid  = threadIdx.x;
    const int lane = tid & 63;
    const int wv   = tid >> 6;
    const int quad = lane >> 4;
    const int ln15 = lane & 15;
    const int m0   = blockIdx.x * 64;
    const int j0   = blockIdx.y * 16;

    // publish the just-completed y column to d_out (one block only)
    if (pubCol >= 0 && blockIdx.x == 0 && blockIdx.y == 0) {
        for (int r = tid; r < NB; r += 256)
            outf[(size_t)r * NT + pubCol] = ybuf[(size_t)r * NT + pubCol];
    }

    // prefetch x for the epilogue rows m = m0 + wv*16 + quad*4 + r
    float xv[4];
    {
        const int mb = m0 + wv * 16 + quad * 4;
        #pragma unroll
        for (int r = 0; r < 4; ++r)
            xv[r] = useY ? ybuf[(size_t)(mb + r) * NT + col]
                         : xin [(size_t)(mb + r) * NT + col];
    }

    f32x4 acc0 = {0.f, 0.f, 0.f, 0.f};
    f32x4 acc1 = {0.f, 0.f, 0.f, 0.f};
    f32x4 acc2 = {0.f, 0.f, 0.f, 0.f};
    f32x4 acc3 = {0.f, 0.f, 0.f, 0.f};

    const int ldr = tid >> 3;   // 0..31
    const int seg = tid & 7;    // 16B segment

    for (int kc = 0; kc < NH; kc += KC) {
        // stage A (h rows m0..m0+63) and B (w_hh0 rows g*512 + j0 + jj)
        *(uint4*)&Ash[ldr][seg * 8] =
            *(const uint4*)(hprev + (size_t)(m0 + ldr) * NH + kc + seg * 8);
        *(uint4*)&Ash[ldr + 32][seg * 8] =
            *(const uint4*)(hprev + (size_t)(m0 + ldr + 32) * NH + kc + seg * 8);
        {
            const int rb0 = ldr, rb1 = ldr + 32;
            const size_t g0 = (size_t)((rb0 >> 4) * NH + j0 + (rb0 & 15)) * NH;
            const size_t g1 = (size_t)((rb1 >> 4) * NH + j0 + (rb1 & 15)) * NH;
            *(uint4*)&Bsh[rb0][seg * 8] = *(const uint4*)(wb0 + g0 + kc + seg * 8);
            *(uint4*)&Bsh[rb1][seg * 8] = *(const uint4*)(wb0 + g1 + kc + seg * 8);
        }
        __syncthreads();
        #pragma unroll
        for (int ks = 0; ks < KC; ks += 32) {
            const bf16x8 af = *(const bf16x8*)&Ash[wv * 16 + ln15][ks + quad * 8];
            const bf16x8 b0 = *(const bf16x8*)&Bsh[ln15][ks + quad * 8];
            const bf16x8 b1 = *(const bf16x8*)&Bsh[16 + ln15][ks + quad * 8];
            const bf16x8 b2 = *(const bf16x8*)&Bsh[32 + ln15][ks + quad * 8];
            const bf16x8 b3 = *(const bf16x8*)&Bsh[48 + ln15][ks + quad * 8];
            acc0 = __builtin_amdgcn_mfma_f32_16x16x32_bf16(af, b0, acc0, 0, 0, 0);
            acc1 = __builtin_amdgcn_mfma_f32_16x16x32_bf16(af, b1, acc1, 0, 0, 0);
            acc2 = __builtin_amdgcn_mfma_f32_16x16x32_bf16(af, b2, acc2, 0, 0, 0);
            acc3 = __builtin_amdgcn_mfma_f32_16x16x32_bf16(af, b3, acc3, 0, 0, 0);
        }
        __syncthreads();
    }

    // epilogue: lane holds all 4 gates for (m = m0+wv*16+quad*4+r, j = j0+ln15)
    const int jv = j0 + ln15;
    const float bi  = bsum0[jv],          bfv = bsum0[NH + jv];
    const float bg  = bsum0[2 * NH + jv], bo  = bsum0[3 * NH + jv];
    const float wxi = wih0f[jv],          wxf = wih0f[NH + jv];
    const float wxg = wih0f[2 * NH + jv], wxo = wih0f[3 * NH + jv];
    #pragma unroll
    for (int r = 0; r < 4; ++r) {
        const int m = m0 + wv * 16 + quad * 4 + r;
        const float gi = acc0[r] + fmaf(xv[r], wxi, bi);
        const float gf = acc1[r] + fmaf(xv[r], wxf, bfv);
        const float gg = acc2[r] + fmaf(xv[r], wxg, bg);
        const float go = acc3[r] + fmaf(xv[r], wxo, bo);
        float cv = c1[(size_t)m * NH + jv];
        cv = lstm7_sig(gf) * cv + lstm7_sig(gi) * tanhf(gg);
        c1[(size_t)m * NH + jv] = cv;
        hnext[(size_t)m * NH + jv] = lstm7_f2b(lstm7_sig(go) * tanhf(cv));
    }
}

// ---- layer-1 MFMA cell: gates = h1 @ w_ih1^T + h2 @ w_hh1^T + bsum1 ----
__global__ __launch_bounds__(256) void lstm7_layer1(
    const unsigned short* __restrict__ h1cur, const unsigned short* __restrict__ h2prev,
    unsigned short* __restrict__ h2next, float* __restrict__ c2,
    const unsigned short* __restrict__ wb1i, const unsigned short* __restrict__ wb1h,
    const float* __restrict__ bsum1, const float* __restrict__ wlinf,
    float* __restrict__ ybuf, int ycol)
{
    __shared__ unsigned short Ash[64][LDK];
    __shared__ unsigned short Bsh[64][LDK];
    __shared__ float redsh[64][17];
    const int tid  = threadIdx.x;
    const int lane = tid & 63;
    const int wv   = tid >> 6;
    const int quad = lane >> 4;
    const int ln15 = lane & 15;
    const int m0   = blockIdx.x * 64;
    const int j0   = blockIdx.y * 16;

    f32x4 acc0 = {0.f, 0.f, 0.f, 0.f};
    f32x4 acc1 = {0.f, 0.f, 0.f, 0.f};
    f32x4 acc2 = {0.f, 0.f, 0.f, 0.f};
    f32x4 acc3 = {0.f, 0.f, 0.f, 0.f};

    const int ldr = tid >> 3;
    const int seg = tid & 7;

    #pragma unroll 1
    for (int ph = 0; ph < 2; ++ph) {
        const unsigned short* ap = ph ? h2prev : h1cur;
        const unsigned short* bp = ph ? wb1h : wb1i;
        for (int kc = 0; kc < NH; kc += KC) {
            *(uint4*)&Ash[ldr][seg * 8] =
                *(const uint4*)(ap + (size_t)(m0 + ldr) * NH + kc + seg * 8);
            *(uint4*)&Ash[ldr + 32][seg * 8] =
                *(const uint4*)(ap + (size_t)(m0 + ldr + 32) * NH + kc + seg * 8);
            {
                const int rb0 = ldr, rb1 = ldr + 32;
                const size_t g0 = (size_t)((rb0 >> 4) * NH + j0 + (rb0 & 15)) * NH;
                const size_t g1 = (size_t)((rb1 >> 4) * NH + j0 + (rb1 & 15)) * NH;
                *(uint4*)&Bsh[rb0][seg * 8] = *(const uint4*)(bp + g0 + kc + seg * 8);
                *(uint4*)&Bsh[rb1][seg * 8] = *(const uint4*)(bp + g1 + kc + seg * 8);
            }
            __syncthreads();
            #pragma unroll
            for (int ks = 0; ks < KC; ks += 32) {
                const bf16x8 af = *(const bf16x8*)&Ash[wv * 16 + ln15][ks + quad * 8];
                const bf16x8 b0 = *(const bf16x8*)&Bsh[ln15][ks + quad * 8];
                const bf16x8 b1 = *(const bf16x8*)&Bsh[16 + ln15][ks + quad * 8];
                const bf16x8 b2 = *(const bf16x8*)&Bsh[32 + ln15][ks + quad * 8];
                const bf16x8 b3 = *(const bf16x8*)&Bsh[48 + ln15][ks + quad * 8];
                acc0 = __builtin_amdgcn_mfma_f32_16x16x32_bf16(af, b0, acc0, 0, 0, 0);
                acc1 = __builtin_amdgcn_mfma_f32_16x16x32_bf16(af, b1, acc1, 0, 0, 0);
                acc2 = __builtin_amdgcn_mfma_f32_16x16x32_bf16(af, b2, acc2, 0, 0, 0);
                acc3 = __builtin_amdgcn_mfma_f32_16x16x32_bf16(af, b3, acc3, 0, 0, 0);
            }
            __syncthreads();
        }
    }

    const int jv = j0 + ln15;
    const float bi  = bsum1[jv],          bfv = bsum1[NH + jv];
    const float bg  = bsum1[2 * NH + jv], bo  = bsum1[3 * NH + jv];
    float hv[4];
    #pragma unroll
    for (int r = 0; r < 4; ++r) {
        const int m = m0 + wv * 16 + quad * 4 + r;
        const float gi = acc0[r] + bi;
        const float gf = acc1[r] + bfv;
        const float gg = acc2[r] + bg;
        const float go = acc3[r] + bo;
        float cv = c2[(size_t)m * NH + jv];
        cv = lstm7_sig(gf) * cv + lstm7_sig(gi) * tanhf(gg);
        c2[(size_t)m * NH + jv] = cv;
        hv[r] = lstm7_sig(go) * tanhf(cv);
        h2next[(size_t)m * NH + jv] = lstm7_f2b(hv[r]);
    }

    if (ycol >= 0) {
        const float wl = wlinf[jv];
        #pragma unroll
        for (int r = 0; r < 4; ++r)
            redsh[wv * 16 + quad * 4 + r][ln15] = hv[r] * wl;
        __syncthreads();
        if (tid < 64) {
            float s = 0.0f;
            #pragma unroll
            for (int j = 0; j < 16; ++j) s += redsh[tid][j];
            atomicAdd(&ybuf[(size_t)(m0 + tid) * NT + ycol], s);
        }
    }
}

// ---- y0 head (reference quirk): y[:,0] = b_lin + c2 @ w_lin (CELL state!) ----
__global__ __launch_bounds__(256) void lstm7_head(
    const float* __restrict__ c2, const float* __restrict__ wlin,
    const float* __restrict__ blin, float* __restrict__ ybuf)
{
    __shared__ float acc[256];
    const int b   = blockIdx.x;
    const int tid = threadIdx.x;
    acc[tid] = c2[(size_t)b * NH + tid]       * wlin[tid]
             + c2[(size_t)b * NH + tid + 256] * wlin[tid + 256];
    __syncthreads();
    for (int off = 128; off > 0; off >>= 1) {
        if (tid < off) acc[tid] += acc[tid + off];
        __syncthreads();
    }
    if (tid == 0) ybuf[(size_t)b * NT] = blin[0] + acc[0];
}

// ---- final: all predictions to d_out as fp32 ----
__global__ void lstm7_emit(const float* __restrict__ ybuf, float* __restrict__ out) {
    const int i = blockIdx.x * blockDim.x + threadIdx.x;
    if (i < NB * NT) out[i] = ybuf[i];
}

extern "C" void kernel_launch(void* const* d_in, const int* in_sizes, int n_in,
                              void* d_out, int out_size, void* d_ws, size_t ws_size,
                              hipStream_t stream)
{
    int base = 3;
    if (!(n_in > 3 && in_sizes[3] == 4 * NH)) {
        for (int i = 1; i + 9 < n_in; ++i)
            if (in_sizes[i] == 4 * NH) { base = i; break; }
    }
    const float* xin  = (const float*)d_in[0];
    const float* wih0 = (const float*)d_in[base + 0];
    const float* whh0 = (const float*)d_in[base + 1];
    const float* bih0 = (const float*)d_in[base + 2];
    const float* bhh0 = (const float*)d_in[base + 3];
    const float* wih1 = (const float*)d_in[base + 4];
    const float* whh1 = (const float*)d_in[base + 5];
    const float* bih1 = (const float*)d_in[base + 6];
    const float* bhh1 = (const float*)d_in[base + 7];
    const float* wlin = (const float*)d_in[base + 8];
    const float* blin = (const float*)d_in[base + 9];
    float* outf = (float*)d_out;

    // ws layout (~10.3 MB): bf16 weights | bf16 h ping-pong | fp32 c, bias, y.
    const size_t NW = (size_t)4 * NH * NH;   // 1M elems
    const size_t S  = (size_t)NB * NH;       // 256K elems
    unsigned short* wb0  = (unsigned short*)d_ws;
    unsigned short* wb1i = wb0 + NW;
    unsigned short* wb1h = wb1i + NW;
    unsigned short* h1b0 = wb1h + NW;
    unsigned short* h1b1 = h1b0 + S;
    unsigned short* h2b0 = h1b1 + S;
    unsigned short* h2b1 = h2b0 + S;
    float* bsum0 = (float*)(h2b1 + S);
    float* bsum1 = bsum0 + 4 * NH;
    float* c1    = bsum1 + 4 * NH;
    float* c2    = c1 + S;
    float* ybuf  = c2 + S;
    unsigned short* h1p[2] = { h1b0, h1b1 };
    unsigned short* h2p[2] = { h2b0, h2b1 };

    lstm7_mark<<<(NB * NT + 255) / 256, 256, 0, stream>>>(outf);
    lstm7_prep<<<1024, 256, 0, stream>>>(whh0, wih1, whh1, bih0, bhh0, bih1, bhh1,
                                         blin, wb0, wb1i, wb1h, bsum0, bsum1,
                                         h1b0 /* 4 h-buffers contiguous */, c1, ybuf);

    dim3 grid(NB / 64, NH / 16);   // 8 x 32 = 256 blocks, 1/CU
    int p = 0;
    // Phase 1: teacher-forced; heads disabled (y0 handled by lstm7_head).
    for (int t = 0; t < NT; ++t) {
        lstm7_layer0<<<grid, 256, 0, stream>>>(xin, ybuf, t, 0, -1, outf,
                                               h1p[p], h1p[p ^ 1], c1,
                                               wb0, bsum0, wih0);
        lstm7_layer1<<<grid, 256, 0, stream>>>(h1p[p ^ 1], h2p[p], h2p[p ^ 1], c2,
                                               wb1i, wb1h, bsum1, wlin, ybuf, -1);
        p ^= 1;
    }
    // Reference quirk: first prediction from the CELL state c2.
    lstm7_head<<<NB, 256, 0, stream>>>(c2, wlin, blin, ybuf);
    // Phase 2: autoregressive; layer0 consumes y[:,k-1] and publishes it.
    for (int k = 1; k < NT; ++k) {
        lstm7_layer0<<<grid, 256, 0, stream>>>(xin, ybuf, k - 1, 1, k - 1, outf,
                                               h1p[p], h1p[p ^ 1], c1,
                                               wb0, bsum0, wih0);
        lstm7_layer1<<<grid, 256, 0, stream>>>(h1p[p ^ 1], h2p[p], h2p[p ^ 1], c2,
                                               wb1i, wb1h, bsum1, wlin, ybuf, k);
        p ^= 1;
    }
    lstm7_emit<<<(NB * NT + 255) / 256, 256, 0, stream>>>(ybuf, outf);
}